// Round 10
// baseline (124.037 us; speedup 1.0000x reference)
//
#include <hip/hip_runtime.h>

// Problem constants
static constexpr int NQ    = 12;
static constexpr int DEPTH = 4;
static constexpr int LAT   = 512;
static constexpr int FAST  = DEPTH * NQ;   // 48
static constexpr float DECAY = 0.9f;

using v2f = __attribute__((ext_vector_type(2))) float;

// One wave = one batch element, 4096 amps in 64 VGPRs/lane, L layout:
// i = (lane<<6) | r ; wire w <-> bit (11-w):
//   wires 0..5 -> lane bits 5..0 (M = 32,16,8,4,2,1)
//   wires 6..11 -> reg bits 5..0 (S = 32,16,8,4,2,1)
// All state stays in registers; LDS is used only for bpermute/swizzle lane
// exchanges (no LDS state buffer -> no WAR hazards, only fine-grained RAW
// lgkmcnt waits which the compiler handles well).

__device__ __forceinline__ float i2f(int x) { return __int_as_float(x); }

// DPP lane-XOR partner (verified r2-r6): M in {1,2,4,8}
template<int M>
__device__ __forceinline__ float dpp_partner(float x) {
    int xi = __float_as_int(x);
    if constexpr (M == 1) {        // quad_perm [1,0,3,2]
        return i2f(__builtin_amdgcn_update_dpp(xi, xi, 0xB1, 0xF, 0xF, true));
    } else if constexpr (M == 2) { // quad_perm [2,3,0,1]
        return i2f(__builtin_amdgcn_update_dpp(xi, xi, 0x4E, 0xF, 0xF, true));
    } else if constexpr (M == 4) { // row_half_mirror (xor7) then quad reverse (xor3)
        int t = __builtin_amdgcn_update_dpp(xi, xi, 0x141, 0xF, 0xF, true);
        return i2f(__builtin_amdgcn_update_dpp(t, t, 0x1B, 0xF, 0xF, true));
    } else {                       // M == 8: row_ror:8 == xor8 within 16-lane rows
        return i2f(__builtin_amdgcn_update_dpp(xi, xi, 0x128, 0xF, 0xF, true));
    }
}

// RY on lane wire with DPP partner fetch: 2 DPP + 2 pk ops per 2 regs
template<int M>
__device__ __forceinline__ void ry_lane_dpp(float (&v)[64], int lane, float c, float s) {
    float t = (lane & M) ? s : -s;
    v2f c2 = {c, c}, t2 = {t, t};
    #pragma unroll
    for (int k = 0; k < 32; k++) {
        float p0 = dpp_partner<M>(v[2 * k]);
        float p1 = dpp_partner<M>(v[2 * k + 1]);
        v2f vv = {v[2 * k], v[2 * k + 1]};
        v2f pp = {p0, p1};
        vv = c2 * vv + t2 * pp;
        v[2 * k]     = vv.x;
        v[2 * k + 1] = vv.y;
    }
}

// RY on lane wire via LDS fetch (bpermute for M=32, swizzle for M=16):
// fetch all partners first (pipelined in the DS queue), then packed math.
template<int M>
__device__ __forceinline__ void ry_lane_lds(float (&v)[64], float (&p)[64],
                                            int lane, int a32, float c, float s) {
    #pragma unroll
    for (int r = 0; r < 64; r++) {
        if constexpr (M == 32)
            p[r] = i2f(__builtin_amdgcn_ds_bpermute(a32, __float_as_int(v[r])));
        else
            p[r] = i2f(__builtin_amdgcn_ds_swizzle(__float_as_int(v[r]), 0x401F)); // xor16
    }
    float t = (lane & M) ? s : -s;
    v2f c2 = {c, c}, t2 = {t, t};
    #pragma unroll
    for (int k = 0; k < 32; k++) {
        v2f vv = {v[2 * k], v[2 * k + 1]};
        v2f pp = {p[2 * k], p[2 * k + 1]};
        vv = c2 * vv + t2 * pp;
        v[2 * k]     = vv.x;
        v[2 * k + 1] = vv.y;
    }
}

// Packed register butterfly, stride S in {2,...,32} (verified r6-r9)
template<int S>
__device__ __forceinline__ void bfly2(float (&v)[64], float c, float s) {
    v2f c2 = {c, c}, s2 = {s, s};
    #pragma unroll
    for (int r0 = 0; r0 < 64; r0 += 2) {
        if ((r0 & S) == 0) {
            v2f a = {v[r0],     v[r0 + 1]};
            v2f b = {v[r0 + S], v[r0 + S + 1]};
            v2f na = c2 * a - s2 * b;
            v2f nb = s2 * a + c2 * b;
            v[r0]     = na.x;  v[r0 + 1]     = na.y;
            v[r0 + S] = nb.x;  v[r0 + S + 1] = nb.y;
        }
    }
}

// Stride-1 butterfly (pair in adjacent regs), verified r6-r9
__device__ __forceinline__ void bfly1(float (&v)[64], float c, float s) {
    v2f cs = {c, s}, nsc = {-s, c};
    #pragma unroll
    for (int r0 = 0; r0 < 64; r0 += 2) {
        float a = v[r0], b = v[r0 + 1];
        v2f aa = {a, a}, bb = {b, b};
        v2f res = cs * aa + nsc * bb;
        v[r0]     = res.x;
        v[r0 + 1] = res.y;
    }
}

// CNOT(W,W+1), W in [6,10]: compile-time register renames (verified r3/r6)
template<int W>
__device__ __forceinline__ void apply_cnot_reg(float (&v)[64]) {
    constexpr int CBS = 1 << (11 - W);
    constexpr int TBS = 1 << (10 - W);
    #pragma unroll
    for (int r = 0; r < 64; r++) {
        if ((r & CBS) != 0 && (r & TBS) == 0) {
            float tmp = v[r];
            v[r]       = v[r | TBS];
            v[r | TBS] = tmp;
        }
    }
}

template<int W>
__device__ __forceinline__ void cnot_reg_chain(float (&v)[64]) {
    if constexpr (W < 11) {
        apply_cnot_reg<W>(v);
        cnot_reg_chain<W + 1>(v);
    }
}

__global__ __launch_bounds__(64, 1)   // (64,1): keep all state in arch VGPRs (r9)
void fwp_kernel(const float* __restrict__ x_t,
                const float* __restrict__ fast_prev,
                const float* __restrict__ W_enc,
                const float* __restrict__ b_enc,
                const float* __restrict__ W_upd,
                const float* __restrict__ b_upd,
                const float* __restrict__ W_ro,
                const float* __restrict__ b_ro,
                float* __restrict__ out_y,
                float* __restrict__ out_fast) {
    const int lane = threadIdx.x;   // block = one wave
    const int b    = blockIdx.x;

    __shared__ __align__(16) float s_lat[LAT];   // 2 KB latent
    __shared__ float s_c[FAST], s_s[FAST];       // per-gate cos/sin

    // ---- x row: wave-uniform scalar loads (verified r7) ----
    const float* xrow = x_t + b * NQ;
    float xa[NQ];
    #pragma unroll
    for (int k = 0; k < NQ; k++) xa[k] = xrow[k];

    // ---- Phase A: latent = tanh(W_enc@x + b_enc), 8 per lane ----
    #pragma unroll
    for (int t = 0; t < LAT / 64; t++) {
        int j = lane + 64 * t;
        const float4* wr = (const float4*)(W_enc + j * NQ);
        float4 a0 = wr[0], a1 = wr[1], a2 = wr[2];
        float sum = b_enc[j]
            + a0.x * xa[0] + a0.y * xa[1] + a0.z * xa[2]  + a0.w * xa[3]
            + a1.x * xa[4] + a1.y * xa[5] + a1.z * xa[6]  + a1.w * xa[7]
            + a2.x * xa[8] + a2.y * xa[9] + a2.z * xa[10] + a2.w * xa[11];
        s_lat[j] = tanhf(sum);
    }

    // ---- Phase B: 48 angles; lane o<48 owns one W_upd row; cos/sin to LDS ----
    if (lane < FAST) {
        const float4* wr = (const float4*)(W_upd + lane * LAT);
        const float4* lr = (const float4*)(s_lat);
        float sum = b_upd[lane];
        #pragma unroll 16
        for (int j = 0; j < LAT / 4; j++) {
            float4 w4 = wr[j];
            float4 l4 = lr[j];   // uniform address -> LDS broadcast
            sum += w4.x * l4.x + w4.y * l4.y + w4.z * l4.z + w4.w * l4.w;
        }
        float ang = DECAY * fast_prev[b * FAST + lane] + sum;
        out_fast[b * FAST + lane] = ang;
        float hh = 0.5f * ang;
        s_c[lane] = __cosf(hh);
        s_s[lane] = __sinf(hh);
    }

    // ---- closed-form product-state init (verified r2-r9) ----
    float g0[NQ], g1[NQ];
    #pragma unroll
    for (int w = 0; w < NQ; w++) {
        float hh = 0.5f * xa[w];
        float c = __cosf(hh), s = __sinf(hh);
        g0[w] = (c - s) * 0.70710678118654752f;
        g1[w] = (c + s) * 0.70710678118654752f;
    }
    float L = 1.0f;
    #pragma unroll
    for (int w = 0; w < 6; w++)
        L *= ((lane >> (5 - w)) & 1) ? g1[w] : g0[w];

    float v[64];
    v[0] = L;
    #pragma unroll
    for (int w = 6; w < NQ; w++) {
        const int S = 1 << (11 - w);
        #pragma unroll
        for (int r = 0; r < 64; r += 2 * S) {
            v[r + S] = v[r] * g1[w];
            v[r]     = v[r] * g0[w];
        }
    }

    // composed lane gather for CNOT(0,1)..(4,5) (verified r3/r6)
    int csrc = lane;
    #pragma unroll
    for (int w = 4; w >= 0; w--)
        csrc ^= ((csrc >> (5 - w)) & 1) << (4 - w);
    const int csrc4 = csrc << 2;
    const int a32   = (lane ^ 32) << 2;   // bpermute addr for M=32 partner

    float p[64];   // partner staging for the LDS-fetch wires

    // ---- 4 layers ----
    #pragma unroll 1   // keep body I-cache resident
    for (int layer = 0; layer < DEPTH; layer++) {
        float lc[NQ], ls[NQ];
        #pragma unroll
        for (int w = 0; w < NQ; w++) {
            lc[w] = s_c[layer * NQ + w];
            ls[w] = s_s[layer * NQ + w];
        }

        // CNOT(0,1)..(4,5): one composed gather per register
        #pragma unroll
        for (int r = 0; r < 64; r++)
            v[r] = i2f(__builtin_amdgcn_ds_bpermute(csrc4, __float_as_int(v[r])));
        // CNOT(5,6): control = lane bit0, target = reg bit5
        bool c5 = (lane & 1) != 0;
        #pragma unroll
        for (int r0 = 0; r0 < 32; r0++) {
            float a = v[r0], bb = v[r0 + 32];
            v[r0]      = c5 ? bb : a;
            v[r0 + 32] = c5 ? a : bb;
        }
        // CNOT(6,7)..(10,11): free register renames
        cnot_reg_chain<6>(v);

        // RY lane wires: LDS-fetch wires first (M=32 bpermute, M=16 swizzle),
        // then DPP wires (M=8,4,2,1)
        ry_lane_lds<32>(v, p, lane, a32, lc[0], ls[0]);   // wire 0
        ry_lane_lds<16>(v, p, lane, a32, lc[1], ls[1]);   // wire 1
        ry_lane_dpp<8>(v, lane, lc[2], ls[2]);            // wire 2
        ry_lane_dpp<4>(v, lane, lc[3], ls[3]);            // wire 3
        ry_lane_dpp<2>(v, lane, lc[4], ls[4]);            // wire 4
        ry_lane_dpp<1>(v, lane, lc[5], ls[5]);            // wire 5

        // RY reg wires 6..11: packed butterflies
        bfly2<32>(v, lc[6],  ls[6]);
        bfly2<16>(v, lc[7],  ls[7]);
        bfly2<8> (v, lc[8],  ls[8]);
        bfly2<4> (v, lc[9],  ls[9]);
        bfly2<2> (v, lc[10], ls[10]);
        bfly1    (v, lc[11], ls[11]);
    }

    // ---- Z expectations folded into readout (verified r5-r9) ----
    float tot = 0.0f, pw[6] = {0, 0, 0, 0, 0, 0};
    #pragma unroll
    for (int r = 0; r < 64; r++) {
        float q = v[r] * v[r];
        tot += q;
        pw[0] += (r & 32) ? -q : q;   // wire 6
        pw[1] += (r & 16) ? -q : q;   // wire 7
        pw[2] += (r & 8)  ? -q : q;   // wire 8
        pw[3] += (r & 4)  ? -q : q;   // wire 9
        pw[4] += (r & 2)  ? -q : q;   // wire 10
        pw[5] += (r & 1)  ? -q : q;   // wire 11
    }
    float sl = 0.0f;
    #pragma unroll
    for (int w = 0; w < 6; w++) {
        float c = W_ro[w];
        sl += ((lane >> (5 - w)) & 1) ? -c : c;
    }
    float y = sl * tot;
    #pragma unroll
    for (int k = 0; k < 6; k++) y += W_ro[6 + k] * pw[k];
    #pragma unroll
    for (int m = 32; m >= 1; m >>= 1) y += __shfl_xor(y, m, 64);
    if (lane == 0) out_y[b] = y + b_ro[0];
}

extern "C" void kernel_launch(void* const* d_in, const int* in_sizes, int n_in,
                              void* d_out, int out_size, void* d_ws, size_t ws_size,
                              hipStream_t stream) {
    const float* x_t       = (const float*)d_in[0];
    const float* fast_prev = (const float*)d_in[1];
    const float* W_enc     = (const float*)d_in[2];
    const float* b_enc     = (const float*)d_in[3];
    const float* W_upd     = (const float*)d_in[4];
    const float* b_upd     = (const float*)d_in[5];
    const float* W_ro      = (const float*)d_in[6];
    const float* b_ro      = (const float*)d_in[7];
    float* out = (float*)d_out;

    fwp_kernel<<<2048, 64, 0, stream>>>(x_t, fast_prev, W_enc, b_enc,
                                        W_upd, b_upd, W_ro, b_ro,
                                        out /*y*/, out + 2048 /*fast_next*/);
}

// Round 11
// 112.832 us; speedup vs baseline: 1.0993x; 1.0993x over previous
//
#include <hip/hip_runtime.h>

// Problem constants
static constexpr int NQ    = 12;
static constexpr int DEPTH = 4;
static constexpr int LAT   = 512;
static constexpr int FAST  = DEPTH * NQ;   // 48
static constexpr float DECAY = 0.9f;
static constexpr int PITCH = 66;           // even (b64 writes), 2-way bank alias = free

using v2f = __attribute__((ext_vector_type(2))) float;

// One wave = one batch element; block = one wave; zero fences (verified r8:
// per-wave DS ops are pipe-ordered; compiler inserts minimal lgkmcnt waits).
// L orientation: i = (lane<<6) | r   (wires 0..5 lane bits, 6..11 reg bits)
// T orientation: i = (r<<6) | lane
// Layer = RY(12) ∘ CNOT-chain(0..10). sigma^-1: bit_p = j_p ^ j_{p+1}.
// Pass 1 folds sigma + L->T into LDS read addressing -> wires 0..5 become
// register butterflies; Pass 2 transposes back -> wires 6..11 register
// butterflies. Stride-32 wire applied last (commutes) so lower-half
// butterflies overlap upper-half reads.
//
// KEY FIX (r10 post-mortem): the allocator was parking the 64-float state in
// AGPRs (VGPR_Count 56-80 across r5-r10), paying v_accvgpr_read/write on
// every gate op (~2-3x VALU inflation, measured). Empty asm with a "+v"
// constraint pins each state element to the arch-VGPR class at zero
// instruction cost; pinned after init and after every LDS read burst.

#define PIN_V(x) asm("" : "+v"(x))

template<int S, int B>
__device__ __forceinline__ void bfly_half(float (&v)[64], float c, float s) {
    v2f c2 = {c, c}, s2 = {s, s};
    #pragma unroll
    for (int r0 = B; r0 < B + 32; r0 += 2) {
        if ((r0 & S) == 0) {
            v2f a = {v[r0],     v[r0 + 1]};
            v2f b = {v[r0 + S], v[r0 + S + 1]};
            v2f na = c2 * a - s2 * b;
            v2f nb = s2 * a + c2 * b;
            v[r0]     = na.x;  v[r0 + 1]     = na.y;
            v[r0 + S] = nb.x;  v[r0 + S + 1] = nb.y;
        }
    }
}

template<int B>
__device__ __forceinline__ void bfly1_half(float (&v)[64], float c, float s) {
    v2f cs = {c, s}, nsc = {-s, c};
    #pragma unroll
    for (int r0 = B; r0 < B + 32; r0 += 2) {
        float a = v[r0], b = v[r0 + 1];
        v2f aa = {a, a}, bb = {b, b};
        v2f res = cs * aa + nsc * bb;   // (c*a - s*b, s*a + c*b)
        v[r0]     = res.x;
        v[r0 + 1] = res.y;
    }
}

// strides 16,8,4,2,1 on half [B, B+32): wires c[0..4]/s[0..4]
template<int B>
__device__ __forceinline__ void ry5_half(float (&v)[64], const float* c, const float* s) {
    bfly_half<16, B>(v, c[0], s[0]);
    bfly_half<8,  B>(v, c[1], s[1]);
    bfly_half<4,  B>(v, c[2], s[2]);
    bfly_half<2,  B>(v, c[3], s[3]);
    bfly1_half<B>(v, c[4], s[4]);
}

// stride-32 butterfly across halves (applied last; commutes with others)
__device__ __forceinline__ void bfly32(float (&v)[64], float c, float s) {
    v2f c2 = {c, c}, s2 = {s, s};
    #pragma unroll
    for (int r0 = 0; r0 < 32; r0 += 2) {
        v2f a = {v[r0],      v[r0 + 1]};
        v2f b = {v[r0 + 32], v[r0 + 33]};
        v2f na = c2 * a - s2 * b;
        v2f nb = s2 * a + c2 * b;
        v[r0]      = na.x;  v[r0 + 1]  = na.y;
        v[r0 + 32] = nb.x;  v[r0 + 33] = nb.y;
    }
}

__global__ __launch_bounds__(64, 1)
void fwp_kernel(const float* __restrict__ x_t,
                const float* __restrict__ fast_prev,
                const float* __restrict__ W_enc,
                const float* __restrict__ b_enc,
                const float* __restrict__ W_upd,
                const float* __restrict__ b_upd,
                const float* __restrict__ W_ro,
                const float* __restrict__ b_ro,
                float* __restrict__ out_y,
                float* __restrict__ out_fast) {
    const int lane = threadIdx.x;   // block = one wave
    const int b    = blockIdx.x;

    __shared__ __align__(16) float s_xch[64 * PITCH];  // 16.9 KB transpose buffer
    __shared__ float s_c[FAST], s_s[FAST];             // per-gate cos/sin

    float* s_lat = s_xch;   // latent reuses the buffer (dead before layer 0)

    // ---- x row: wave-uniform scalar loads (verified r7) ----
    const float* xrow = x_t + b * NQ;
    float xa[NQ];
    #pragma unroll
    for (int k = 0; k < NQ; k++) xa[k] = xrow[k];

    // ---- Phase A: latent = tanh(W_enc@x + b_enc), 8 per lane ----
    #pragma unroll
    for (int t = 0; t < LAT / 64; t++) {
        int j = lane + 64 * t;
        const float4* wr = (const float4*)(W_enc + j * NQ);
        float4 a0 = wr[0], a1 = wr[1], a2 = wr[2];
        float sum = b_enc[j]
            + a0.x * xa[0] + a0.y * xa[1] + a0.z * xa[2]  + a0.w * xa[3]
            + a1.x * xa[4] + a1.y * xa[5] + a1.z * xa[6]  + a1.w * xa[7]
            + a2.x * xa[8] + a2.y * xa[9] + a2.z * xa[10] + a2.w * xa[11];
        s_lat[j] = tanhf(sum);
    }

    // ---- Phase B: 48 angles; lane o<48 owns one W_upd row; cos/sin to LDS ----
    if (lane < FAST) {
        const float4* wr = (const float4*)(W_upd + lane * LAT);
        const float4* lr = (const float4*)(s_lat);
        float sum = b_upd[lane];
        #pragma unroll 16
        for (int j = 0; j < LAT / 4; j++) {
            float4 w4 = wr[j];
            float4 l4 = lr[j];   // uniform address -> LDS broadcast
            sum += w4.x * l4.x + w4.y * l4.y + w4.z * l4.z + w4.w * l4.w;
        }
        float ang = DECAY * fast_prev[b * FAST + lane] + sum;
        out_fast[b * FAST + lane] = ang;
        float hh = 0.5f * ang;
        s_c[lane] = __cosf(hh);
        s_s[lane] = __sinf(hh);
    }

    // ---- closed-form product-state init (verified r2-r10) ----
    float g0[NQ], g1[NQ];
    #pragma unroll
    for (int w = 0; w < NQ; w++) {
        float hh = 0.5f * xa[w];
        float c = __cosf(hh), s = __sinf(hh);
        g0[w] = (c - s) * 0.70710678118654752f;
        g1[w] = (c + s) * 0.70710678118654752f;
    }
    float L = 1.0f;
    #pragma unroll
    for (int w = 0; w < 6; w++)
        L *= ((lane >> (5 - w)) & 1) ? g1[w] : g0[w];

    float v[64];
    v[0] = L;
    #pragma unroll
    for (int w = 6; w < NQ; w++) {
        const int S = 1 << (11 - w);
        #pragma unroll
        for (int r = 0; r < 64; r += 2 * S) {
            v[r + S] = v[r] * g1[w];
            v[r]     = v[r] * g0[w];
        }
    }
    #pragma unroll
    for (int r = 0; r < 64; r++) PIN_V(v[r]);   // state lives in arch VGPRs

    // Pass-1 read bases (verified r5/r7/r8)
    const int A0 = ((lane ^ (lane >> 1)) & 31) | (lane & 32);
    const int A1 = A0 ^ 32;

    // ---- 4 layers, fully unrolled, zero fences ----
    #pragma unroll
    for (int layer = 0; layer < DEPTH; layer++) {
        float lc[NQ], ls[NQ];
        #pragma unroll
        for (int w = 0; w < NQ; w++) {
            lc[w] = s_c[layer * NQ + w];
            ls[w] = s_s[layer * NQ + w];
        }

        // -------- Pass 1: sigma + L->T folded into read addressing --------
        #pragma unroll
        for (int k = 0; k < 32; k++)
            *(v2f*)&s_xch[lane * PITCH + 2 * k] = (v2f){v[2 * k], v[2 * k + 1]};
        #pragma unroll
        for (int r = 0; r < 32; r++) {
            const int g = r ^ (r >> 1);
            v[r] = s_xch[g * PITCH + ((r & 1) ? A1 : A0)];
        }
        #pragma unroll
        for (int r = 0; r < 32; r++) PIN_V(v[r]);
        ry5_half<0>(v, lc + 1, ls + 1);      // wires 1..5 on lower half
        #pragma unroll
        for (int r = 32; r < 64; r++) {
            const int g = r ^ (r >> 1);
            v[r] = s_xch[g * PITCH + ((r & 1) ? A1 : A0)];
        }
        #pragma unroll
        for (int r = 32; r < 64; r++) PIN_V(v[r]);
        ry5_half<32>(v, lc + 1, ls + 1);     // wires 1..5 on upper half
        bfly32(v, lc[0], ls[0]);             // wire 0 last (commutes)

        // -------- Pass 2: plain transpose T->L --------
        #pragma unroll
        for (int k = 0; k < 32; k++)
            *(v2f*)&s_xch[lane * PITCH + 2 * k] = (v2f){v[2 * k], v[2 * k + 1]};
        #pragma unroll
        for (int r = 0; r < 32; r++) v[r] = s_xch[r * PITCH + lane];
        #pragma unroll
        for (int r = 0; r < 32; r++) PIN_V(v[r]);
        ry5_half<0>(v, lc + 7, ls + 7);      // wires 7..11 on lower half
        #pragma unroll
        for (int r = 32; r < 64; r++) v[r] = s_xch[r * PITCH + lane];
        #pragma unroll
        for (int r = 32; r < 64; r++) PIN_V(v[r]);
        ry5_half<32>(v, lc + 7, ls + 7);     // wires 7..11 on upper half
        bfly32(v, lc[6], ls[6]);             // wire 6 last (commutes)
    }

    // ---- Z expectations folded into readout (verified r5-r10) ----
    float tot = 0.0f, pw[6] = {0, 0, 0, 0, 0, 0};
    #pragma unroll
    for (int r = 0; r < 64; r++) {
        float p = v[r] * v[r];
        tot += p;
        pw[0] += (r & 32) ? -p : p;   // wire 6
        pw[1] += (r & 16) ? -p : p;   // wire 7
        pw[2] += (r & 8)  ? -p : p;   // wire 8
        pw[3] += (r & 4)  ? -p : p;   // wire 9
        pw[4] += (r & 2)  ? -p : p;   // wire 10
        pw[5] += (r & 1)  ? -p : p;   // wire 11
    }
    float sl = 0.0f;
    #pragma unroll
    for (int w = 0; w < 6; w++) {
        float c = W_ro[w];
        sl += ((lane >> (5 - w)) & 1) ? -c : c;
    }
    float y = sl * tot;
    #pragma unroll
    for (int k = 0; k < 6; k++) y += W_ro[6 + k] * pw[k];
    #pragma unroll
    for (int m = 32; m >= 1; m >>= 1) y += __shfl_xor(y, m, 64);
    if (lane == 0) out_y[b] = y + b_ro[0];
}

extern "C" void kernel_launch(void* const* d_in, const int* in_sizes, int n_in,
                              void* d_out, int out_size, void* d_ws, size_t ws_size,
                              hipStream_t stream) {
    const float* x_t       = (const float*)d_in[0];
    const float* fast_prev = (const float*)d_in[1];
    const float* W_enc     = (const float*)d_in[2];
    const float* b_enc     = (const float*)d_in[3];
    const float* W_upd     = (const float*)d_in[4];
    const float* b_upd     = (const float*)d_in[5];
    const float* W_ro      = (const float*)d_in[6];
    const float* b_ro      = (const float*)d_in[7];
    float* out = (float*)d_out;

    fwp_kernel<<<2048, 64, 0, stream>>>(x_t, fast_prev, W_enc, b_enc,
                                        W_upd, b_upd, W_ro, b_ro,
                                        out /*y*/, out + 2048 /*fast_next*/);
}

// Round 12
// 112.297 us; speedup vs baseline: 1.1045x; 1.0048x over previous
//
#include <hip/hip_runtime.h>

// Problem constants
static constexpr int NQ    = 12;
static constexpr int DEPTH = 4;
static constexpr int LAT   = 512;
static constexpr int FAST  = DEPTH * NQ;   // 48
static constexpr float DECAY = 0.9f;
static constexpr int PITCH = 66;           // even (b64 writes), 2-way bank alias = free

using v2f = __attribute__((ext_vector_type(2))) float;

// One wave = one batch element; block = one wave; zero fences (r8-verified:
// per-wave DS ops are pipe-ordered, compiler inserts the minimal lgkmcnt).
// L orientation: i = (lane<<6) | r   (wires 0..5 lane bits, 6..11 reg bits)
// T orientation: i = (r<<6) | lane
// Layer = RY(12) ∘ CNOT-chain(0..10). sigma^-1: bit_p = j_p ^ j_{p+1}.
// Pass 1 folds sigma + L->T into LDS read addressing -> wires 0..5 become
// register butterflies; Pass 2 transposes back -> wires 6..11 register
// butterflies. Stride-32 wire last (commutes) so lower-half butterflies
// overlap upper-half reads.
//
// r12 EXPERIMENT: all 8 co-resident waves/CU run identical code in lockstep,
// alternating DS-burst and VALU phases together -> both pipes ~35% busy
// (measured r7/r8/r11). s_sleep stagger by blockIdx&3 (~450 cyc/step) pushes
// waves into anti-phase so one group's butterflies cover another's DS bursts.

template<int S, int B>
__device__ __forceinline__ void bfly_half(float (&v)[64], float c, float s) {
    v2f c2 = {c, c}, s2 = {s, s};
    #pragma unroll
    for (int r0 = B; r0 < B + 32; r0 += 2) {
        if ((r0 & S) == 0) {
            v2f a = {v[r0],     v[r0 + 1]};
            v2f b = {v[r0 + S], v[r0 + S + 1]};
            v2f na = c2 * a - s2 * b;
            v2f nb = s2 * a + c2 * b;
            v[r0]     = na.x;  v[r0 + 1]     = na.y;
            v[r0 + S] = nb.x;  v[r0 + S + 1] = nb.y;
        }
    }
}

template<int B>
__device__ __forceinline__ void bfly1_half(float (&v)[64], float c, float s) {
    v2f cs = {c, s}, nsc = {-s, c};
    #pragma unroll
    for (int r0 = B; r0 < B + 32; r0 += 2) {
        float a = v[r0], b = v[r0 + 1];
        v2f aa = {a, a}, bb = {b, b};
        v2f res = cs * aa + nsc * bb;   // (c*a - s*b, s*a + c*b)
        v[r0]     = res.x;
        v[r0 + 1] = res.y;
    }
}

// strides 16,8,4,2,1 on half [B, B+32): wires cs[0..4]
template<int B>
__device__ __forceinline__ void ry5_half(float (&v)[64], const v2f* cs) {
    bfly_half<16, B>(v, cs[0].x, cs[0].y);
    bfly_half<8,  B>(v, cs[1].x, cs[1].y);
    bfly_half<4,  B>(v, cs[2].x, cs[2].y);
    bfly_half<2,  B>(v, cs[3].x, cs[3].y);
    bfly1_half<B>(v, cs[4].x, cs[4].y);
}

// stride-32 butterfly across halves (applied last; commutes)
__device__ __forceinline__ void bfly32(float (&v)[64], float c, float s) {
    v2f c2 = {c, c}, s2 = {s, s};
    #pragma unroll
    for (int r0 = 0; r0 < 32; r0 += 2) {
        v2f a = {v[r0],      v[r0 + 1]};
        v2f b = {v[r0 + 32], v[r0 + 33]};
        v2f na = c2 * a - s2 * b;
        v2f nb = s2 * a + c2 * b;
        v[r0]      = na.x;  v[r0 + 1]  = na.y;
        v[r0 + 32] = nb.x;  v[r0 + 33] = nb.y;
    }
}

__global__ __launch_bounds__(64, 1)
void fwp_kernel(const float* __restrict__ x_t,
                const float* __restrict__ fast_prev,
                const float* __restrict__ W_enc,
                const float* __restrict__ b_enc,
                const float* __restrict__ W_upd,
                const float* __restrict__ b_upd,
                const float* __restrict__ W_ro,
                const float* __restrict__ b_ro,
                float* __restrict__ out_y,
                float* __restrict__ out_fast) {
    const int lane = threadIdx.x;   // block = one wave
    const int b    = blockIdx.x;

    __shared__ __align__(16) float s_xch[64 * PITCH];  // 16.9 KB transpose buffer
    __shared__ __align__(8)  v2f   s_cs[FAST];         // per-gate (cos, sin)

    float* s_lat = s_xch;   // latent reuses the buffer (dead before layer 0)

    // ---- anti-lockstep stagger: ~450 cyc per step, by block parity class ----
    {
        const int ph = b & 3;
        if (ph > 0) __builtin_amdgcn_s_sleep(7);
        if (ph > 1) __builtin_amdgcn_s_sleep(7);
        if (ph > 2) __builtin_amdgcn_s_sleep(7);
    }

    // ---- x row: wave-uniform scalar loads (verified r7) ----
    const float* xrow = x_t + b * NQ;
    float xa[NQ];
    #pragma unroll
    for (int k = 0; k < NQ; k++) xa[k] = xrow[k];

    // ---- Phase A: latent = tanh(W_enc@x + b_enc), 8 per lane ----
    #pragma unroll
    for (int t = 0; t < LAT / 64; t++) {
        int j = lane + 64 * t;
        const float4* wr = (const float4*)(W_enc + j * NQ);
        float4 a0 = wr[0], a1 = wr[1], a2 = wr[2];
        float sum = b_enc[j]
            + a0.x * xa[0] + a0.y * xa[1] + a0.z * xa[2]  + a0.w * xa[3]
            + a1.x * xa[4] + a1.y * xa[5] + a1.z * xa[6]  + a1.w * xa[7]
            + a2.x * xa[8] + a2.y * xa[9] + a2.z * xa[10] + a2.w * xa[11];
        s_lat[j] = tanhf(sum);
    }

    // ---- Phase B: 48 angles; lane o<48 owns one W_upd row; (cos,sin) to LDS ----
    if (lane < FAST) {
        const float4* wr = (const float4*)(W_upd + lane * LAT);
        const float4* lr = (const float4*)(s_lat);
        float sum = b_upd[lane];
        #pragma unroll 16
        for (int j = 0; j < LAT / 4; j++) {
            float4 w4 = wr[j];
            float4 l4 = lr[j];   // uniform address -> LDS broadcast
            sum += w4.x * l4.x + w4.y * l4.y + w4.z * l4.z + w4.w * l4.w;
        }
        float ang = DECAY * fast_prev[b * FAST + lane] + sum;
        out_fast[b * FAST + lane] = ang;
        float hh = 0.5f * ang;
        s_cs[lane] = (v2f){__cosf(hh), __sinf(hh)};
    }

    // ---- closed-form product-state init (verified r2-r11) ----
    float g0[NQ], g1[NQ];
    #pragma unroll
    for (int w = 0; w < NQ; w++) {
        float hh = 0.5f * xa[w];
        float c = __cosf(hh), s = __sinf(hh);
        g0[w] = (c - s) * 0.70710678118654752f;
        g1[w] = (c + s) * 0.70710678118654752f;
    }
    float L = 1.0f;
    #pragma unroll
    for (int w = 0; w < 6; w++)
        L *= ((lane >> (5 - w)) & 1) ? g1[w] : g0[w];

    float v[64];
    v[0] = L;
    #pragma unroll
    for (int w = 6; w < NQ; w++) {
        const int S = 1 << (11 - w);
        #pragma unroll
        for (int r = 0; r < 64; r += 2 * S) {
            v[r + S] = v[r] * g1[w];
            v[r]     = v[r] * g0[w];
        }
    }

    // Pass-1 read bases (verified r5/r7/r8)
    const int A0 = ((lane ^ (lane >> 1)) & 31) | (lane & 32);
    const int A1 = A0 ^ 32;

    // ---- 4 layers, fully unrolled, zero fences ----
    #pragma unroll
    for (int layer = 0; layer < DEPTH; layer++) {
        v2f cs[NQ];
        #pragma unroll
        for (int w = 0; w < NQ; w++) cs[w] = s_cs[layer * NQ + w];

        // -------- Pass 1: sigma + L->T folded into read addressing --------
        #pragma unroll
        for (int k = 0; k < 32; k++)
            *(v2f*)&s_xch[lane * PITCH + 2 * k] = (v2f){v[2 * k], v[2 * k + 1]};
        #pragma unroll
        for (int r = 0; r < 32; r++) {
            const int g = r ^ (r >> 1);
            v[r] = s_xch[g * PITCH + ((r & 1) ? A1 : A0)];
        }
        ry5_half<0>(v, cs + 1);              // wires 1..5 on lower half
        #pragma unroll
        for (int r = 32; r < 64; r++) {
            const int g = r ^ (r >> 1);
            v[r] = s_xch[g * PITCH + ((r & 1) ? A1 : A0)];
        }
        ry5_half<32>(v, cs + 1);             // wires 1..5 on upper half
        bfly32(v, cs[0].x, cs[0].y);         // wire 0 last (commutes)

        // -------- Pass 2: plain transpose T->L --------
        #pragma unroll
        for (int k = 0; k < 32; k++)
            *(v2f*)&s_xch[lane * PITCH + 2 * k] = (v2f){v[2 * k], v[2 * k + 1]};
        #pragma unroll
        for (int r = 0; r < 32; r++) v[r] = s_xch[r * PITCH + lane];
        ry5_half<0>(v, cs + 7);              // wires 7..11 on lower half
        #pragma unroll
        for (int r = 32; r < 64; r++) v[r] = s_xch[r * PITCH + lane];
        ry5_half<32>(v, cs + 7);             // wires 7..11 on upper half
        bfly32(v, cs[6].x, cs[6].y);         // wire 6 last (commutes)
    }

    // ---- Z expectations folded into readout (verified r5-r11) ----
    float tot = 0.0f, pw[6] = {0, 0, 0, 0, 0, 0};
    #pragma unroll
    for (int r = 0; r < 64; r++) {
        float p = v[r] * v[r];
        tot += p;
        pw[0] += (r & 32) ? -p : p;   // wire 6
        pw[1] += (r & 16) ? -p : p;   // wire 7
        pw[2] += (r & 8)  ? -p : p;   // wire 8
        pw[3] += (r & 4)  ? -p : p;   // wire 9
        pw[4] += (r & 2)  ? -p : p;   // wire 10
        pw[5] += (r & 1)  ? -p : p;   // wire 11
    }
    float sl = 0.0f;
    #pragma unroll
    for (int w = 0; w < 6; w++) {
        float c = W_ro[w];
        sl += ((lane >> (5 - w)) & 1) ? -c : c;
    }
    float y = sl * tot;
    #pragma unroll
    for (int k = 0; k < 6; k++) y += W_ro[6 + k] * pw[k];
    #pragma unroll
    for (int m = 32; m >= 1; m >>= 1) y += __shfl_xor(y, m, 64);
    if (lane == 0) out_y[b] = y + b_ro[0];
}

extern "C" void kernel_launch(void* const* d_in, const int* in_sizes, int n_in,
                              void* d_out, int out_size, void* d_ws, size_t ws_size,
                              hipStream_t stream) {
    const float* x_t       = (const float*)d_in[0];
    const float* fast_prev = (const float*)d_in[1];
    const float* W_enc     = (const float*)d_in[2];
    const float* b_enc     = (const float*)d_in[3];
    const float* W_upd     = (const float*)d_in[4];
    const float* b_upd     = (const float*)d_in[5];
    const float* W_ro      = (const float*)d_in[6];
    const float* b_ro      = (const float*)d_in[7];
    float* out = (float*)d_out;

    fwp_kernel<<<2048, 64, 0, stream>>>(x_t, fast_prev, W_enc, b_enc,
                                        W_upd, b_upd, W_ro, b_ro,
                                        out /*y*/, out + 2048 /*fast_next*/);
}

// Round 13
// 106.221 us; speedup vs baseline: 1.1677x; 1.0572x over previous
//
#include <hip/hip_runtime.h>

// Problem constants
static constexpr int NQ    = 12;
static constexpr int DEPTH = 4;
static constexpr int LAT   = 512;
static constexpr int FAST  = DEPTH * NQ;   // 48
static constexpr float DECAY = 0.9f;
static constexpr int P     = 68;           // row pitch (floats): 272 B = 16B-aligned

using v2f = __attribute__((ext_vector_type(2))) float;

// ONE WAVE = TWO batch elements, separate LDS buffers (no WAR coupling).
// L orientation: i = (lane<<6) | r (wires 0..5 lane bits, 6..11 reg bits); T swaps.
// Layer = RY(12) ∘ CNOT-chain(0..10); sigma^-1: bit_p = j_p ^ j_{p+1}.
// Pass 1: b128 row-writes + sigma-and-transpose-folded b32 scatter reads
//   (r5/r8-verified formula; immediate offsets only).
// Pass 2: b32 scatter-writes (transpose folded into write addr, imm offsets)
//   + b128 row-reads.
// Butterfly RYs between passes (r8-verified ordering: strides 16..1 per half,
// stride-32 wire last — RYs on distinct wires commute).

template<int S, int B>
__device__ __forceinline__ void bfly_half(float (&v)[64], float c, float s) {
    v2f c2 = {c, c}, s2 = {s, s};
    #pragma unroll
    for (int r0 = B; r0 < B + 32; r0 += 2) {
        if ((r0 & S) == 0) {
            v2f a = {v[r0],     v[r0 + 1]};
            v2f b = {v[r0 + S], v[r0 + S + 1]};
            v2f na = c2 * a - s2 * b;
            v2f nb = s2 * a + c2 * b;
            v[r0]     = na.x;  v[r0 + 1]     = na.y;
            v[r0 + S] = nb.x;  v[r0 + S + 1] = nb.y;
        }
    }
}

template<int B>
__device__ __forceinline__ void bfly1_half(float (&v)[64], float c, float s) {
    v2f cs = {c, s}, nsc = {-s, c};
    #pragma unroll
    for (int r0 = B; r0 < B + 32; r0 += 2) {
        float a = v[r0], b = v[r0 + 1];
        v2f aa = {a, a}, bb = {b, b};
        v2f res = cs * aa + nsc * bb;   // (c*a - s*b, s*a + c*b)
        v[r0]     = res.x;
        v[r0 + 1] = res.y;
    }
}

template<int B>
__device__ __forceinline__ void ry5_half(float (&v)[64], const v2f* cs) {
    bfly_half<16, B>(v, cs[0].x, cs[0].y);
    bfly_half<8,  B>(v, cs[1].x, cs[1].y);
    bfly_half<4,  B>(v, cs[2].x, cs[2].y);
    bfly_half<2,  B>(v, cs[3].x, cs[3].y);
    bfly1_half<B>(v, cs[4].x, cs[4].y);
}

__device__ __forceinline__ void bfly32(float (&v)[64], float c, float s) {
    v2f c2 = {c, c}, s2 = {s, s};
    #pragma unroll
    for (int r0 = 0; r0 < 32; r0 += 2) {
        v2f a = {v[r0],      v[r0 + 1]};
        v2f b = {v[r0 + 32], v[r0 + 33]};
        v2f na = c2 * a - s2 * b;
        v2f nb = s2 * a + c2 * b;
        v[r0]      = na.x;  v[r0 + 1]  = na.y;
        v[r0 + 32] = nb.x;  v[r0 + 33] = nb.y;
    }
}

// Pass 1: write L rows wide, read back with sigma + L->T folded (verified).
__device__ __forceinline__ void pass1(float (&v)[64], float* X, int lane, int A0, int A1) {
    #pragma unroll
    for (int k = 0; k < 16; k++)
        *(float4*)&X[lane * P + 4 * k] =
            (float4){v[4 * k], v[4 * k + 1], v[4 * k + 2], v[4 * k + 3]};
    #pragma unroll
    for (int r = 0; r < 64; r++) {
        const int g = r ^ (r >> 1);                 // compile-time imm offset
        v[r] = X[g * P + ((r & 1) ? A1 : A0)];
    }
}

// Pass 2: transpose via b32 scatter-writes (imm offsets) + b128 row-reads.
__device__ __forceinline__ void pass2(float (&v)[64], float* X, int lane) {
    #pragma unroll
    for (int q = 0; q < 64; q++) X[q * P + lane] = v[q];   // addr = lane*4 + imm
    #pragma unroll
    for (int k = 0; k < 16; k++) {
        float4 t = *(const float4*)&X[lane * P + 4 * k];
        v[4 * k]     = t.x;  v[4 * k + 1] = t.y;
        v[4 * k + 2] = t.z;  v[4 * k + 3] = t.w;
    }
}

// closed-form product state from the 12 initial RYs (verified r2-r12)
__device__ __forceinline__ void init_state(float (&v)[64], const float (&xa)[NQ], int lane) {
    float g0[NQ], g1[NQ];
    #pragma unroll
    for (int w = 0; w < NQ; w++) {
        float hh = 0.5f * xa[w];
        float c = __cosf(hh), s = __sinf(hh);
        g0[w] = (c - s) * 0.70710678118654752f;
        g1[w] = (c + s) * 0.70710678118654752f;
    }
    float L = 1.0f;
    #pragma unroll
    for (int w = 0; w < 6; w++)
        L *= ((lane >> (5 - w)) & 1) ? g1[w] : g0[w];
    v[0] = L;
    #pragma unroll
    for (int w = 6; w < NQ; w++) {
        const int S = 1 << (11 - w);
        #pragma unroll
        for (int r = 0; r < 64; r += 2 * S) {
            v[r + S] = v[r] * g1[w];
            v[r]     = v[r] * g0[w];
        }
    }
}

__global__ __launch_bounds__(64, 1)
void fwp_kernel(const float* __restrict__ x_t,
                const float* __restrict__ fast_prev,
                const float* __restrict__ W_enc,
                const float* __restrict__ b_enc,
                const float* __restrict__ W_upd,
                const float* __restrict__ b_upd,
                const float* __restrict__ W_ro,
                const float* __restrict__ b_ro,
                float* __restrict__ out_y,
                float* __restrict__ out_fast) {
    const int lane = threadIdx.x;          // block = one wave
    const int eA   = 2 * blockIdx.x;
    const int eB   = eA + 1;

    __shared__ __align__(16) float XA[64 * P];   // 17408 B
    __shared__ __align__(16) float XB[64 * P];   // 17408 B
    __shared__ __align__(8)  v2f   csA[FAST], csB[FAST];

    float* latA = XA;   // latents carved from circuit buffers (dead later)
    float* latB = XB;

    // ---- x rows (wave-uniform scalar loads, verified r7) ----
    float xaA[NQ], xaB[NQ];
    #pragma unroll
    for (int k = 0; k < NQ; k++) {
        xaA[k] = x_t[eA * NQ + k];
        xaB[k] = x_t[eB * NQ + k];
    }

    // ---- Phase A: lane owns latents j = 8*lane .. 8*lane+7 (contiguous) ----
    {
        const float4* we = (const float4*)(W_enc + lane * 8 * NQ);  // 8 rows, 384 B
        float4 be0 = *(const float4*)&b_enc[8 * lane];
        float4 be1 = *(const float4*)&b_enc[8 * lane + 4];
        float be[8] = {be0.x, be0.y, be0.z, be0.w, be1.x, be1.y, be1.z, be1.w};
        float lA[8], lB[8];
        #pragma unroll
        for (int t = 0; t < 8; t++) {
            float4 a0 = we[3 * t], a1 = we[3 * t + 1], a2 = we[3 * t + 2];
            float sA = be[t]
                + a0.x * xaA[0] + a0.y * xaA[1] + a0.z * xaA[2]  + a0.w * xaA[3]
                + a1.x * xaA[4] + a1.y * xaA[5] + a1.z * xaA[6]  + a1.w * xaA[7]
                + a2.x * xaA[8] + a2.y * xaA[9] + a2.z * xaA[10] + a2.w * xaA[11];
            float sB = be[t]
                + a0.x * xaB[0] + a0.y * xaB[1] + a0.z * xaB[2]  + a0.w * xaB[3]
                + a1.x * xaB[4] + a1.y * xaB[5] + a1.z * xaB[6]  + a1.w * xaB[7]
                + a2.x * xaB[8] + a2.y * xaB[9] + a2.z * xaB[10] + a2.w * xaB[11];
            lA[t] = tanhf(sA);
            lB[t] = tanhf(sB);
        }
        *(float4*)&latA[8 * lane]     = (float4){lA[0], lA[1], lA[2], lA[3]};
        *(float4*)&latA[8 * lane + 4] = (float4){lA[4], lA[5], lA[6], lA[7]};
        *(float4*)&latB[8 * lane]     = (float4){lB[0], lB[1], lB[2], lB[3]};
        *(float4*)&latB[8 * lane + 4] = (float4){lB[4], lB[5], lB[6], lB[7]};
    }

    // ---- Phase B: 48 angles per element; W_upd row loaded once ----
    if (lane < FAST) {
        const float4* wr = (const float4*)(W_upd + lane * LAT);
        const float4* la = (const float4*)(latA);
        const float4* lb = (const float4*)(latB);
        float base = b_upd[lane];
        float sA = base, sB = base;
        #pragma unroll 8
        for (int j = 0; j < LAT / 4; j++) {
            float4 w4 = wr[j];
            float4 a4 = la[j];   // uniform -> broadcast
            float4 b4 = lb[j];
            sA += w4.x * a4.x + w4.y * a4.y + w4.z * a4.z + w4.w * a4.w;
            sB += w4.x * b4.x + w4.y * b4.y + w4.z * b4.z + w4.w * b4.w;
        }
        float angA = DECAY * fast_prev[eA * FAST + lane] + sA;
        float angB = DECAY * fast_prev[eB * FAST + lane] + sB;
        out_fast[eA * FAST + lane] = angA;
        out_fast[eB * FAST + lane] = angB;
        csA[lane] = (v2f){__cosf(0.5f * angA), __sinf(0.5f * angA)};
        csB[lane] = (v2f){__cosf(0.5f * angB), __sinf(0.5f * angB)};
    }

    // ---- product states ----
    float vA[64], vB[64];
    init_state(vA, xaA, lane);
    init_state(vB, xaB, lane);

    const int A0 = ((lane ^ (lane >> 1)) & 31) | (lane & 32);
    const int A1 = A0 ^ 32;

    // ---- 4 layers; per-element sections keep each lgkm queue short ----
    #pragma unroll 1
    for (int layer = 0; layer < DEPTH; layer++) {
        v2f ca[NQ], cb[NQ];
        #pragma unroll
        for (int w = 0; w < NQ; w++) {
            ca[w] = csA[layer * NQ + w];
            cb[w] = csB[layer * NQ + w];
        }

        // element A, pass 1 + wires 1..5, 0 (T orientation)
        pass1(vA, XA, lane, A0, A1);
        ry5_half<0>(vA, ca + 1);
        ry5_half<32>(vA, ca + 1);
        bfly32(vA, ca[0].x, ca[0].y);
        // element B, pass 1
        pass1(vB, XB, lane, A0, A1);
        ry5_half<0>(vB, cb + 1);
        ry5_half<32>(vB, cb + 1);
        bfly32(vB, cb[0].x, cb[0].y);
        // element A, pass 2 + wires 7..11, 6 (L orientation)
        pass2(vA, XA, lane);
        ry5_half<0>(vA, ca + 7);
        ry5_half<32>(vA, ca + 7);
        bfly32(vA, ca[6].x, ca[6].y);
        // element B, pass 2
        pass2(vB, XB, lane);
        ry5_half<0>(vB, cb + 7);
        ry5_half<32>(vB, cb + 7);
        bfly32(vB, cb[6].x, cb[6].y);
    }

    // ---- Z expectations folded into readout, both elements (verified r9) ----
    float wro[NQ];
    #pragma unroll
    for (int w = 0; w < NQ; w++) wro[w] = W_ro[w];
    float sl = 0.0f;
    #pragma unroll
    for (int w = 0; w < 6; w++)
        sl += ((lane >> (5 - w)) & 1) ? -wro[w] : wro[w];

    float totA = 0.0f, pwA[6] = {0,0,0,0,0,0};
    float totB = 0.0f, pwB[6] = {0,0,0,0,0,0};
    #pragma unroll
    for (int r = 0; r < 64; r++) {
        float pA = vA[r] * vA[r];
        float pB = vB[r] * vB[r];
        totA += pA;  totB += pB;
        pwA[0] += (r & 32) ? -pA : pA;  pwB[0] += (r & 32) ? -pB : pB;
        pwA[1] += (r & 16) ? -pA : pA;  pwB[1] += (r & 16) ? -pB : pB;
        pwA[2] += (r & 8)  ? -pA : pA;  pwB[2] += (r & 8)  ? -pB : pB;
        pwA[3] += (r & 4)  ? -pA : pA;  pwB[3] += (r & 4)  ? -pB : pB;
        pwA[4] += (r & 2)  ? -pA : pA;  pwB[4] += (r & 2)  ? -pB : pB;
        pwA[5] += (r & 1)  ? -pA : pA;  pwB[5] += (r & 1)  ? -pB : pB;
    }
    float yA = sl * totA, yB = sl * totB;
    #pragma unroll
    for (int k = 0; k < 6; k++) {
        yA += wro[6 + k] * pwA[k];
        yB += wro[6 + k] * pwB[k];
    }
    #pragma unroll
    for (int m = 32; m >= 1; m >>= 1) {
        yA += __shfl_xor(yA, m, 64);
        yB += __shfl_xor(yB, m, 64);
    }
    if (lane == 0) {
        float br = b_ro[0];
        out_y[eA] = yA + br;
        out_y[eB] = yB + br;
    }
}

extern "C" void kernel_launch(void* const* d_in, const int* in_sizes, int n_in,
                              void* d_out, int out_size, void* d_ws, size_t ws_size,
                              hipStream_t stream) {
    const float* x_t       = (const float*)d_in[0];
    const float* fast_prev = (const float*)d_in[1];
    const float* W_enc     = (const float*)d_in[2];
    const float* b_enc     = (const float*)d_in[3];
    const float* W_upd     = (const float*)d_in[4];
    const float* b_upd     = (const float*)d_in[5];
    const float* W_ro      = (const float*)d_in[6];
    const float* b_ro      = (const float*)d_in[7];
    float* out = (float*)d_out;

    // 1024 blocks x 1 wave, 2 batch elements per wave, 4 blocks/CU
    fwp_kernel<<<1024, 64, 0, stream>>>(x_t, fast_prev, W_enc, b_enc,
                                        W_upd, b_upd, W_ro, b_ro,
                                        out /*y*/, out + 2048 /*fast_next*/);
}

// Round 14
// 106.133 us; speedup vs baseline: 1.1687x; 1.0008x over previous
//
#include <hip/hip_runtime.h>

// Problem constants
static constexpr int NQ    = 12;
static constexpr int DEPTH = 4;
static constexpr int LAT   = 512;
static constexpr int FAST  = DEPTH * NQ;   // 48
static constexpr float DECAY = 0.9f;
static constexpr int P     = 68;           // row pitch (floats): 272 B, 16B-aligned

using v2f = __attribute__((ext_vector_type(2))) float;

// ONE WAVE = TWO batch elements (A,B), separate LDS buffers.
// L orientation: i = (lane<<6) | r (wires 0..5 lane bits, 6..11 reg bits); T swaps.
// Layer = RY(12) ∘ CNOT-chain(0..10); sigma^-1: bit_p = j_p ^ j_{p+1}.
// Pass 1: b128 row-writes + sigma-and-transpose-folded b32 reads (verified).
// Pass 2: b32 scatter-writes + b128 row-reads (verified r13).
//
// r14 KEY CHANGE: DS bursts for A and B are manually interleaved in source
// (wA, wB, rA, rB, then butterflies A, butterflies B). The compiler's
// conservative LDS aliasing preserves source order and never hoists B's DS
// ops over A's (r9/r13 lesson), so the overlap must be written literally.
// The wait before A's butterflies clamps to lgkmcnt(15) with B's reads
// outstanding -> B's reads land under A's ~770-cyc butterfly block.

template<int S, int B>
__device__ __forceinline__ void bfly_half(float (&v)[64], float c, float s) {
    v2f c2 = {c, c}, s2 = {s, s};
    #pragma unroll
    for (int r0 = B; r0 < B + 32; r0 += 2) {
        if ((r0 & S) == 0) {
            v2f a = {v[r0],     v[r0 + 1]};
            v2f b = {v[r0 + S], v[r0 + S + 1]};
            v2f na = c2 * a - s2 * b;
            v2f nb = s2 * a + c2 * b;
            v[r0]     = na.x;  v[r0 + 1]     = na.y;
            v[r0 + S] = nb.x;  v[r0 + S + 1] = nb.y;
        }
    }
}

template<int B>
__device__ __forceinline__ void bfly1_half(float (&v)[64], float c, float s) {
    v2f cs = {c, s}, nsc = {-s, c};
    #pragma unroll
    for (int r0 = B; r0 < B + 32; r0 += 2) {
        float a = v[r0], b = v[r0 + 1];
        v2f aa = {a, a}, bb = {b, b};
        v2f res = cs * aa + nsc * bb;   // (c*a - s*b, s*a + c*b)
        v[r0]     = res.x;
        v[r0 + 1] = res.y;
    }
}

template<int B>
__device__ __forceinline__ void ry5_half(float (&v)[64], const v2f* cs) {
    bfly_half<16, B>(v, cs[0].x, cs[0].y);
    bfly_half<8,  B>(v, cs[1].x, cs[1].y);
    bfly_half<4,  B>(v, cs[2].x, cs[2].y);
    bfly_half<2,  B>(v, cs[3].x, cs[3].y);
    bfly1_half<B>(v, cs[4].x, cs[4].y);
}

__device__ __forceinline__ void bfly32(float (&v)[64], float c, float s) {
    v2f c2 = {c, c}, s2 = {s, s};
    #pragma unroll
    for (int r0 = 0; r0 < 32; r0 += 2) {
        v2f a = {v[r0],      v[r0 + 1]};
        v2f b = {v[r0 + 32], v[r0 + 33]};
        v2f na = c2 * a - s2 * b;
        v2f nb = s2 * a + c2 * b;
        v[r0]      = na.x;  v[r0 + 1]  = na.y;
        v[r0 + 32] = nb.x;  v[r0 + 33] = nb.y;
    }
}

// full 6-wire butterfly block for one orientation (wires cs[0..5], cs[0]=stride32)
__device__ __forceinline__ void ry6(float (&v)[64], const v2f* cs) {
    ry5_half<0>(v, cs + 1);
    ry5_half<32>(v, cs + 1);
    bfly32(v, cs[0].x, cs[0].y);   // stride-32 wire last (commutes)
}

// pass-1 pieces (verified r13)
__device__ __forceinline__ void p1w(const float (&v)[64], float* X, int lane) {
    #pragma unroll
    for (int k = 0; k < 16; k++)
        *(float4*)&X[lane * P + 4 * k] =
            (float4){v[4 * k], v[4 * k + 1], v[4 * k + 2], v[4 * k + 3]};
}
__device__ __forceinline__ void p1r(float (&v)[64], const float* X, int A0, int A1) {
    #pragma unroll
    for (int r = 0; r < 64; r++) {
        const int g = r ^ (r >> 1);                 // compile-time imm offset
        v[r] = X[g * P + ((r & 1) ? A1 : A0)];
    }
}
// pass-2 pieces (verified r13)
__device__ __forceinline__ void p2w(const float (&v)[64], float* X, int lane) {
    #pragma unroll
    for (int q = 0; q < 64; q++) X[q * P + lane] = v[q];   // addr = lane*4 + imm
}
__device__ __forceinline__ void p2r(float (&v)[64], const float* X, int lane) {
    #pragma unroll
    for (int k = 0; k < 16; k++) {
        float4 t = *(const float4*)&X[lane * P + 4 * k];
        v[4 * k]     = t.x;  v[4 * k + 1] = t.y;
        v[4 * k + 2] = t.z;  v[4 * k + 3] = t.w;
    }
}

// closed-form product state from the 12 initial RYs (verified r2-r13)
__device__ __forceinline__ void init_state(float (&v)[64], const float (&xa)[NQ], int lane) {
    float g0[NQ], g1[NQ];
    #pragma unroll
    for (int w = 0; w < NQ; w++) {
        float hh = 0.5f * xa[w];
        float c = __cosf(hh), s = __sinf(hh);
        g0[w] = (c - s) * 0.70710678118654752f;
        g1[w] = (c + s) * 0.70710678118654752f;
    }
    float L = 1.0f;
    #pragma unroll
    for (int w = 0; w < 6; w++)
        L *= ((lane >> (5 - w)) & 1) ? g1[w] : g0[w];
    v[0] = L;
    #pragma unroll
    for (int w = 6; w < NQ; w++) {
        const int S = 1 << (11 - w);
        #pragma unroll
        for (int r = 0; r < 64; r += 2 * S) {
            v[r + S] = v[r] * g1[w];
            v[r]     = v[r] * g0[w];
        }
    }
}

__global__ __launch_bounds__(64, 1)
void fwp_kernel(const float* __restrict__ x_t,
                const float* __restrict__ fast_prev,
                const float* __restrict__ W_enc,
                const float* __restrict__ b_enc,
                const float* __restrict__ W_upd,
                const float* __restrict__ b_upd,
                const float* __restrict__ W_ro,
                const float* __restrict__ b_ro,
                float* __restrict__ out_y,
                float* __restrict__ out_fast) {
    const int lane = threadIdx.x;          // block = one wave
    const int eA   = 2 * blockIdx.x;
    const int eB   = eA + 1;

    __shared__ __align__(16) float XA[64 * P];   // 17408 B
    __shared__ __align__(16) float XB[64 * P];   // 17408 B
    __shared__ __align__(8)  v2f   csA[FAST], csB[FAST];

    float* latA = XA;   // latents carved from circuit buffers (dead later)
    float* latB = XB;

    // ---- x rows (wave-uniform scalar loads, verified r7) ----
    float xaA[NQ], xaB[NQ];
    #pragma unroll
    for (int k = 0; k < NQ; k++) {
        xaA[k] = x_t[eA * NQ + k];
        xaB[k] = x_t[eB * NQ + k];
    }

    // ---- Phase A: lane owns latents j = 8*lane..8*lane+7 (verified r13) ----
    {
        const float4* we = (const float4*)(W_enc + lane * 8 * NQ);  // 8 rows, 384 B
        float4 be0 = *(const float4*)&b_enc[8 * lane];
        float4 be1 = *(const float4*)&b_enc[8 * lane + 4];
        float be[8] = {be0.x, be0.y, be0.z, be0.w, be1.x, be1.y, be1.z, be1.w};
        float lA[8], lB[8];
        #pragma unroll
        for (int t = 0; t < 8; t++) {
            float4 a0 = we[3 * t], a1 = we[3 * t + 1], a2 = we[3 * t + 2];
            float sA = be[t]
                + a0.x * xaA[0] + a0.y * xaA[1] + a0.z * xaA[2]  + a0.w * xaA[3]
                + a1.x * xaA[4] + a1.y * xaA[5] + a1.z * xaA[6]  + a1.w * xaA[7]
                + a2.x * xaA[8] + a2.y * xaA[9] + a2.z * xaA[10] + a2.w * xaA[11];
            float sB = be[t]
                + a0.x * xaB[0] + a0.y * xaB[1] + a0.z * xaB[2]  + a0.w * xaB[3]
                + a1.x * xaB[4] + a1.y * xaB[5] + a1.z * xaB[6]  + a1.w * xaB[7]
                + a2.x * xaB[8] + a2.y * xaB[9] + a2.z * xaB[10] + a2.w * xaB[11];
            lA[t] = tanhf(sA);
            lB[t] = tanhf(sB);
        }
        *(float4*)&latA[8 * lane]     = (float4){lA[0], lA[1], lA[2], lA[3]};
        *(float4*)&latA[8 * lane + 4] = (float4){lA[4], lA[5], lA[6], lA[7]};
        *(float4*)&latB[8 * lane]     = (float4){lB[0], lB[1], lB[2], lB[3]};
        *(float4*)&latB[8 * lane + 4] = (float4){lB[4], lB[5], lB[6], lB[7]};
    }

    // ---- Phase B: 48 angles per element; W_upd row loaded once ----
    if (lane < FAST) {
        const float4* wr = (const float4*)(W_upd + lane * LAT);
        const float4* la = (const float4*)(latA);
        const float4* lb = (const float4*)(latB);
        float base = b_upd[lane];
        float sA = base, sB = base;
        #pragma unroll 8
        for (int j = 0; j < LAT / 4; j++) {
            float4 w4 = wr[j];
            float4 a4 = la[j];   // uniform -> broadcast
            float4 b4 = lb[j];
            sA += w4.x * a4.x + w4.y * a4.y + w4.z * a4.z + w4.w * a4.w;
            sB += w4.x * b4.x + w4.y * b4.y + w4.z * b4.z + w4.w * b4.w;
        }
        float angA = DECAY * fast_prev[eA * FAST + lane] + sA;
        float angB = DECAY * fast_prev[eB * FAST + lane] + sB;
        out_fast[eA * FAST + lane] = angA;
        out_fast[eB * FAST + lane] = angB;
        csA[lane] = (v2f){__cosf(0.5f * angA), __sinf(0.5f * angA)};
        csB[lane] = (v2f){__cosf(0.5f * angB), __sinf(0.5f * angB)};
    }

    // ---- product states ----
    float vA[64], vB[64];
    init_state(vA, xaA, lane);
    init_state(vB, xaB, lane);

    const int A0 = ((lane ^ (lane >> 1)) & 31) | (lane & 32);
    const int A1 = A0 ^ 32;

    // ---- 4 layers; DS bursts A/B interleaved, butterflies cover tails ----
    #pragma unroll 1
    for (int layer = 0; layer < DEPTH; layer++) {
        v2f ca[NQ], cb[NQ];
        #pragma unroll
        for (int w = 0; w < NQ; w++) {
            ca[w] = csA[layer * NQ + w];
            cb[w] = csB[layer * NQ + w];
        }

        // -------- pass 1 (sigma + L->T): fused DS bursts, then math --------
        p1w(vA, XA, lane);
        p1w(vB, XB, lane);
        p1r(vA, XA, A0, A1);
        p1r(vB, XB, A0, A1);     // outstanding while A's butterflies run
        ry6(vA, ca);             // waits lgkmcnt(15): 49/64 B-reads already done
        ry6(vB, cb);             // B's reads landed under A's math

        // -------- pass 2 (transpose back): fused DS bursts, then math --------
        p2w(vA, XA, lane);
        p2w(vB, XB, lane);
        p2r(vA, XA, lane);
        p2r(vB, XB, lane);
        ry6(vA, ca + 6);
        ry6(vB, cb + 6);
    }

    // ---- Z expectations folded into readout, both elements (verified r9) ----
    float wro[NQ];
    #pragma unroll
    for (int w = 0; w < NQ; w++) wro[w] = W_ro[w];
    float sl = 0.0f;
    #pragma unroll
    for (int w = 0; w < 6; w++)
        sl += ((lane >> (5 - w)) & 1) ? -wro[w] : wro[w];

    float totA = 0.0f, pwA[6] = {0,0,0,0,0,0};
    float totB = 0.0f, pwB[6] = {0,0,0,0,0,0};
    #pragma unroll
    for (int r = 0; r < 64; r++) {
        float pA = vA[r] * vA[r];
        float pB = vB[r] * vB[r];
        totA += pA;  totB += pB;
        pwA[0] += (r & 32) ? -pA : pA;  pwB[0] += (r & 32) ? -pB : pB;
        pwA[1] += (r & 16) ? -pA : pA;  pwB[1] += (r & 16) ? -pB : pB;
        pwA[2] += (r & 8)  ? -pA : pA;  pwB[2] += (r & 8)  ? -pB : pB;
        pwA[3] += (r & 4)  ? -pA : pA;  pwB[3] += (r & 4)  ? -pB : pB;
        pwA[4] += (r & 2)  ? -pA : pA;  pwB[4] += (r & 2)  ? -pB : pB;
        pwA[5] += (r & 1)  ? -pA : pA;  pwB[5] += (r & 1)  ? -pB : pB;
    }
    float yA = sl * totA, yB = sl * totB;
    #pragma unroll
    for (int k = 0; k < 6; k++) {
        yA += wro[6 + k] * pwA[k];
        yB += wro[6 + k] * pwB[k];
    }
    #pragma unroll
    for (int m = 32; m >= 1; m >>= 1) {
        yA += __shfl_xor(yA, m, 64);
        yB += __shfl_xor(yB, m, 64);
    }
    if (lane == 0) {
        float br = b_ro[0];
        out_y[eA] = yA + br;
        out_y[eB] = yB + br;
    }
}

extern "C" void kernel_launch(void* const* d_in, const int* in_sizes, int n_in,
                              void* d_out, int out_size, void* d_ws, size_t ws_size,
                              hipStream_t stream) {
    const float* x_t       = (const float*)d_in[0];
    const float* fast_prev = (const float*)d_in[1];
    const float* W_enc     = (const float*)d_in[2];
    const float* b_enc     = (const float*)d_in[3];
    const float* W_upd     = (const float*)d_in[4];
    const float* b_upd     = (const float*)d_in[5];
    const float* W_ro      = (const float*)d_in[6];
    const float* b_ro      = (const float*)d_in[7];
    float* out = (float*)d_out;

    // 1024 blocks x 1 wave, 2 batch elements per wave
    fwp_kernel<<<1024, 64, 0, stream>>>(x_t, fast_prev, W_enc, b_enc,
                                        W_upd, b_upd, W_ro, b_ro,
                                        out /*y*/, out + 2048 /*fast_next*/);
}